// Round 9
// baseline (510.626 us; speedup 1.0000x reference)
//
#include <hip/hip_runtime.h>

#define D 2048
#define DD ((size_t)D * (size_t)D)

typedef __attribute__((ext_vector_type(8))) short bf16x8;
typedef __attribute__((ext_vector_type(16))) float f32x16;

#define GLOBAL_AS __attribute__((address_space(1)))
#define LDS_AS __attribute__((address_space(3)))

__device__ inline unsigned short f2bf(float f) {
  unsigned u = __float_as_uint(f);
  u += 0x7fffu + ((u >> 16) & 1u);
  return (unsigned short)(u >> 16);
}

// ---------------------------------------------------------------------------
__global__ void init_vecs(const float* __restrict__ b_upper5,
                          const float* __restrict__ b_lower5,
                          const float* __restrict__ ub5,
                          const float* __restrict__ lb5,
                          float* __restrict__ bu, float* __restrict__ bl,
                          float* __restrict__ out) {
  int t = blockIdx.x * blockDim.x + threadIdx.x;
  if (t < D) {
    bu[t] = b_upper5[t];
    bl[t] = b_lower5[t];
    out[t] = ub5[t];
    out[D + t] = lb5[t];
  }
}

// ---------------------------------------------------------------------------
// prep: fused per-iteration prep pass (unchanged, proven).
//   blocks [0, 2048):   concretize row r + write bf16 copies of Wu/Wl rows
//   blocks [2048, 3072): conv_B 64x64 tile -> BsT/BdT (transposed bf16)
// ---------------------------------------------------------------------------
__global__ __launch_bounds__(256) void prep(
    const float* __restrict__ Wu, const float* __restrict__ Wl,
    const float* __restrict__ ubi, const float* __restrict__ lbi,
    const float* __restrict__ bupi, const float* __restrict__ bloi,
    float* __restrict__ bu, float* __restrict__ bl,
    float* __restrict__ best,
    unsigned short* __restrict__ oU, unsigned short* __restrict__ oL,
    const float* __restrict__ Wup, const float* __restrict__ Wlo,
    unsigned short* __restrict__ BsT, unsigned short* __restrict__ BdT,
    int update_bias, int write16) {
  __shared__ float red[4][4];
  __shared__ unsigned short sS[64][68];
  __shared__ unsigned short sD[64][68];

  const int t = threadIdx.x;

  if (blockIdx.x < 2048) {
    const int r = blockIdx.x;
    const size_t base = (size_t)r * D + t * 8;
    const int c = t * 8;

    float4 wu0 = *(const float4*)(Wu + base), wu1 = *(const float4*)(Wu + base + 4);
    float4 wl0 = *(const float4*)(Wl + base), wl1 = *(const float4*)(Wl + base + 4);
    float4 u0 = *(const float4*)(ubi + c),  u1 = *(const float4*)(ubi + c + 4);
    float4 l0 = *(const float4*)(lbi + c),  l1 = *(const float4*)(lbi + c + 4);
    float4 p0 = *(const float4*)(bupi + c), p1 = *(const float4*)(bupi + c + 4);
    float4 n0 = *(const float4*)(bloi + c), n1 = *(const float4*)(bloi + c + 4);

    float wu[8] = {wu0.x, wu0.y, wu0.z, wu0.w, wu1.x, wu1.y, wu1.z, wu1.w};
    float wl[8] = {wl0.x, wl0.y, wl0.z, wl0.w, wl1.x, wl1.y, wl1.z, wl1.w};
    float uu[8] = {u0.x, u0.y, u0.z, u0.w, u1.x, u1.y, u1.z, u1.w};
    float ll[8] = {l0.x, l0.y, l0.z, l0.w, l1.x, l1.y, l1.z, l1.w};
    float pp[8] = {p0.x, p0.y, p0.z, p0.w, p1.x, p1.y, p1.z, p1.w};
    float nn[8] = {n0.x, n0.y, n0.z, n0.w, n1.x, n1.y, n1.z, n1.w};

    float su_c = 0.f, su_b = 0.f, sl_c = 0.f, sl_b = 0.f;
    #pragma unroll
    for (int j = 0; j < 8; ++j) {
      su_c += wu[j] * (wu[j] >= 0.f ? uu[j] : ll[j]);
      su_b += wu[j] * (wu[j] >= 0.f ? pp[j] : nn[j]);
      sl_c += wl[j] * (wl[j] >= 0.f ? ll[j] : uu[j]);
      sl_b += wl[j] * (wl[j] >= 0.f ? nn[j] : pp[j]);
    }

    if (write16) {
      uint4 w;
      w.x = f2bf(wu[0]) | ((unsigned)f2bf(wu[1]) << 16);
      w.y = f2bf(wu[2]) | ((unsigned)f2bf(wu[3]) << 16);
      w.z = f2bf(wu[4]) | ((unsigned)f2bf(wu[5]) << 16);
      w.w = f2bf(wu[6]) | ((unsigned)f2bf(wu[7]) << 16);
      *(uint4*)(oU + base) = w;
      w.x = f2bf(wl[0]) | ((unsigned)f2bf(wl[1]) << 16);
      w.y = f2bf(wl[2]) | ((unsigned)f2bf(wl[3]) << 16);
      w.z = f2bf(wl[4]) | ((unsigned)f2bf(wl[5]) << 16);
      w.w = f2bf(wl[6]) | ((unsigned)f2bf(wl[7]) << 16);
      *(uint4*)(oL + base) = w;
    }

    #pragma unroll
    for (int off = 32; off; off >>= 1) {
      su_c += __shfl_down(su_c, off);
      su_b += __shfl_down(su_b, off);
      sl_c += __shfl_down(sl_c, off);
      sl_b += __shfl_down(sl_b, off);
    }
    int wave = t >> 6;
    if ((t & 63) == 0) {
      red[0][wave] = su_c; red[1][wave] = su_b;
      red[2][wave] = sl_c; red[3][wave] = sl_b;
    }
    __syncthreads();
    if (t == 0) {
      float a = red[0][0] + red[0][1] + red[0][2] + red[0][3];
      float b = red[1][0] + red[1][1] + red[1][2] + red[1][3];
      float cc = red[2][0] + red[2][1] + red[2][2] + red[2][3];
      float d = red[3][0] + red[3][1] + red[3][2] + red[3][3];
      float bu_old = bu[r], bl_old = bl[r];
      best[r]     = fminf(best[r],     a + bu_old);
      best[D + r] = fmaxf(best[D + r], cc + bl_old);
      if (update_bias) {
        bu[r] = b + bu_old;
        bl[r] = d + bl_old;
      }
    }
  } else {
    const int bx = blockIdx.x - 2048;
    const int k0 = (bx >> 5) * 64, c0 = (bx & 31) * 64;
    const int tx = t & 15, ty = t >> 4;
    #pragma unroll
    for (int r = 0; r < 4; ++r) {
      int kk = ty + r * 16;
      size_t g = (size_t)(k0 + kk) * D + c0 + tx * 4;
      float4 up = *(const float4*)(Wup + g);
      float4 lo = *(const float4*)(Wlo + g);
      sS[kk][tx * 4 + 0] = f2bf((up.x + lo.x) * 0.5f);
      sS[kk][tx * 4 + 1] = f2bf((up.y + lo.y) * 0.5f);
      sS[kk][tx * 4 + 2] = f2bf((up.z + lo.z) * 0.5f);
      sS[kk][tx * 4 + 3] = f2bf((up.w + lo.w) * 0.5f);
      sD[kk][tx * 4 + 0] = f2bf((up.x - lo.x) * 0.5f);
      sD[kk][tx * 4 + 1] = f2bf((up.y - lo.y) * 0.5f);
      sD[kk][tx * 4 + 2] = f2bf((up.z - lo.z) * 0.5f);
      sD[kk][tx * 4 + 3] = f2bf((up.w - lo.w) * 0.5f);
    }
    __syncthreads();
    #pragma unroll
    for (int r = 0; r < 4; ++r) {
      int cc = ty + r * 16;
      int kq = tx * 4;
      unsigned a0 = sS[kq + 0][cc] | ((unsigned)sS[kq + 1][cc] << 16);
      unsigned a1 = sS[kq + 2][cc] | ((unsigned)sS[kq + 3][cc] << 16);
      *(uint2*)(BsT + (size_t)(c0 + cc) * D + k0 + kq) = make_uint2(a0, a1);
      a0 = sD[kq + 0][cc] | ((unsigned)sD[kq + 1][cc] << 16);
      a1 = sD[kq + 2][cc] | ((unsigned)sD[kq + 3][cc] << 16);
      *(uint2*)(BdT + (size_t)(c0 + cc) * D + k0 + kq) = make_uint2(a0, a1);
    }
  }
}

// ---------------------------------------------------------------------------
// Fused dual GEMM — counted-vmcnt pipeline (T3+T4+T5).
// BK=32, 4 LDS buffers x 32KB (streams AU|AL|Bs|Bd, [128 rows][32 k] bf16),
// 3-tiles-deep prefetch. Per tile: s_waitcnt vmcnt(8) (never 0 in steady
// state) + raw s_barrier (no drain), then 2 phases of
// {6 ds_read || 2 glds-issue for t+3 || setprio(1) 8 MFMA setprio(0)}.
// Row = 4 x 16B slots, swizzle slot ^= (row & 3) on stage-source and read.
// ---------------------------------------------------------------------------
__global__ __launch_bounds__(512, 2) void gemm_fused(
    const unsigned short* __restrict__ w16U,
    const unsigned short* __restrict__ w16L,
    const unsigned short* __restrict__ BsT,
    const unsigned short* __restrict__ BdT,
    float* __restrict__ Cu, float* __restrict__ Cl) {
  extern __shared__ unsigned char lds[];

  const int bid = blockIdx.x;
  const int vid = (bid & 7) * 32 + (bid >> 3);   // bijective XCD swizzle (256%8==0)
  const int row0 = (vid >> 4) * 128, col0 = (vid & 15) * 128;

  const int tid = threadIdx.x;
  const int lane = tid & 63, wid = tid >> 6;
  const int grp = wid >> 2;            // 0 = upper path, 1 = lower path
  const int w2 = wid & 3;
  const int wr = w2 >> 1, wc = w2 & 1; // 64x64 sub-tile coords
  const int l31 = lane & 31, kh = lane >> 5;

  // staging: per stream, wave wid owns chunk wid (16 rows x 64B = 1KB).
  const int rowc = wid * 16 + (lane >> 2);
  const int swel = ((lane & 3) ^ (rowc & 3)) * 8;  // pre-swizzled source elems
  const unsigned short* gAU = w16U + (size_t)(row0 + rowc) * D + swel;
  const unsigned short* gAL = w16L + (size_t)(row0 + rowc) * D + swel;
  const unsigned short* gBs = BsT + (size_t)(col0 + rowc) * D + swel;
  const unsigned short* gBd = BdT + (size_t)(col0 + rowc) * D + swel;

  f32x16 acc[2][2] = {};

  // fragment byte offsets within a stream (row*64B, slot=(ks*2+kh)^(row&3))
  int aoff[2][2], boff[2][2];
  #pragma unroll
  for (int mb = 0; mb < 2; ++mb) {
    int ar = wr * 64 + mb * 32 + l31;
    #pragma unroll
    for (int ks = 0; ks < 2; ++ks)
      aoff[mb][ks] = ar * 64 + (((ks * 2 + kh) ^ (ar & 3)) * 16);
  }
  #pragma unroll
  for (int nb = 0; nb < 2; ++nb) {
    int bc = wc * 64 + nb * 32 + l31;
    #pragma unroll
    for (int ks = 0; ks < 2; ++ks)
      boff[nb][ks] = bc * 64 + (((ks * 2 + kh) ^ (bc & 3)) * 16);
  }

  #define STAGE_A(buf, kt)                                                        \
    do {                                                                          \
      unsigned dst = (unsigned)(buf) * 32768u + (unsigned)wid * 1024u;            \
      __builtin_amdgcn_global_load_lds((const GLOBAL_AS unsigned*)(gAU + (kt)),   \
          (LDS_AS unsigned*)(lds + 0 + dst), 16, 0, 0);                           \
      __builtin_amdgcn_global_load_lds((const GLOBAL_AS unsigned*)(gAL + (kt)),   \
          (LDS_AS unsigned*)(lds + 8192 + dst), 16, 0, 0);                        \
    } while (0)
  #define STAGE_B(buf, kt)                                                        \
    do {                                                                          \
      unsigned dst = (unsigned)(buf) * 32768u + (unsigned)wid * 1024u;            \
      __builtin_amdgcn_global_load_lds((const GLOBAL_AS unsigned*)(gBs + (kt)),   \
          (LDS_AS unsigned*)(lds + 16384 + dst), 16, 0, 0);                       \
      __builtin_amdgcn_global_load_lds((const GLOBAL_AS unsigned*)(gBd + (kt)),   \
          (LDS_AS unsigned*)(lds + 24576 + dst), 16, 0, 0);                       \
    } while (0)

  // prologue: stage tiles 0,1,2 into buffers 0,1,2 (12 loads in flight)
  STAGE_A(0, 0);  STAGE_B(0, 0);
  STAGE_A(1, 32); STAGE_B(1, 32);
  STAGE_A(2, 64); STAGE_B(2, 64);

  const unsigned Abase = grp ? 8192u : 0u;
  for (int t = 0; t < 64; ++t) {
    // wait for tile t's 4 loads only; keep t+1, t+2 in flight
    if (t < 62)       asm volatile("s_waitcnt vmcnt(8)" ::: "memory");
    else if (t == 62) asm volatile("s_waitcnt vmcnt(4)" ::: "memory");
    else              asm volatile("s_waitcnt vmcnt(0)" ::: "memory");
    __builtin_amdgcn_s_barrier();

    const unsigned char* Ab = lds + Abase + (t & 3) * 32768;
    const unsigned char* Sb = lds + 16384 + (t & 3) * 32768;
    const unsigned char* Db = lds + 24576 + (t & 3) * 32768;
    const bool do_stage = (t <= 60);

    #pragma unroll
    for (int ks = 0; ks < 2; ++ks) {
      bf16x8 aw0 = *(const bf16x8*)(Ab + aoff[0][ks]);
      bf16x8 aw1 = *(const bf16x8*)(Ab + aoff[1][ks]);
      bf16x8 bs0 = *(const bf16x8*)(Sb + boff[0][ks]);
      bf16x8 bs1 = *(const bf16x8*)(Sb + boff[1][ks]);
      bf16x8 bd0 = *(const bf16x8*)(Db + boff[0][ks]);
      bf16x8 bd1 = *(const bf16x8*)(Db + boff[1][ks]);

      if (do_stage) {
        if (ks == 0) STAGE_A((t + 3) & 3, (t + 3) * 32);
        else         STAGE_B((t + 3) & 3, (t + 3) * 32);
      }

      if (grp) { bd0 ^= (short)0x8000; bd1 ^= (short)0x8000; }
      bf16x8 av0 = aw0 & (short)0x7fff;
      bf16x8 av1 = aw1 & (short)0x7fff;

      __builtin_amdgcn_s_setprio(1);
      acc[0][0] = __builtin_amdgcn_mfma_f32_32x32x16_bf16(aw0, bs0, acc[0][0], 0, 0, 0);
      acc[0][0] = __builtin_amdgcn_mfma_f32_32x32x16_bf16(av0, bd0, acc[0][0], 0, 0, 0);
      acc[0][1] = __builtin_amdgcn_mfma_f32_32x32x16_bf16(aw0, bs1, acc[0][1], 0, 0, 0);
      acc[0][1] = __builtin_amdgcn_mfma_f32_32x32x16_bf16(av0, bd1, acc[0][1], 0, 0, 0);
      acc[1][0] = __builtin_amdgcn_mfma_f32_32x32x16_bf16(aw1, bs0, acc[1][0], 0, 0, 0);
      acc[1][0] = __builtin_amdgcn_mfma_f32_32x32x16_bf16(av1, bd0, acc[1][0], 0, 0, 0);
      acc[1][1] = __builtin_amdgcn_mfma_f32_32x32x16_bf16(aw1, bs1, acc[1][1], 0, 0, 0);
      acc[1][1] = __builtin_amdgcn_mfma_f32_32x32x16_bf16(av1, bd1, acc[1][1], 0, 0, 0);
      __builtin_amdgcn_s_setprio(0);
    }
  }
  #undef STAGE_A
  #undef STAGE_B

  // epilogue: C/D layout col=lane&31, row=(reg&3)+8*(reg>>2)+4*(lane>>5)
  float* C = grp ? Cl : Cu;
  #pragma unroll
  for (int mb = 0; mb < 2; ++mb)
    #pragma unroll
    for (int nb = 0; nb < 2; ++nb) {
      const int colg = col0 + wc * 64 + nb * 32 + l31;
      const int rowb = row0 + wr * 64 + mb * 32 + kh * 4;
      #pragma unroll
      for (int g = 0; g < 4; ++g)
        #pragma unroll
        for (int j = 0; j < 4; ++j)
          C[(size_t)(rowb + g * 8 + j) * D + colg] = acc[mb][nb][g * 4 + j];
    }
}

// ---------------------------------------------------------------------------
extern "C" void kernel_launch(void* const* d_in, const int* in_sizes, int n_in,
                              void* d_out, int out_size, void* d_ws, size_t ws_size,
                              hipStream_t stream) {
  const float* W_upper = (const float*)d_in[0];
  const float* W_lower = (const float*)d_in[1];
  const float* b_upper = (const float*)d_in[2];
  const float* b_lower = (const float*)d_in[3];
  const float* ub      = (const float*)d_in[4];
  const float* lb      = (const float*)d_in[5];
  float* out = (float*)d_out;
  float* ws  = (float*)d_ws;

  float* curU = ws;                                       // DD f32
  float* curL = ws + DD;                                  // DD f32
  unsigned short* w16U = (unsigned short*)(ws + 2 * DD);  // DD bf16
  unsigned short* w16L = w16U + DD;
  unsigned short* BsT  = w16L + DD;
  unsigned short* BdT  = BsT + DD;
  float* bu = (float*)(BdT + DD);                         // D f32
  float* bl = bu + D;

  static_cast<void>(hipFuncSetAttribute(
      (const void*)gemm_fused, hipFuncAttributeMaxDynamicSharedMemorySize, 131072));

  init_vecs<<<(D + 255) / 256, 256, 0, stream>>>(
      b_upper + 5 * D, b_lower + 5 * D, ub + 5 * D, lb + 5 * D, bu, bl, out);

  const float* cU = W_upper + 5 * DD;
  const float* cL = W_lower + 5 * DD;
  for (int i = 4; i >= 0; --i) {
    prep<<<3072, 256, 0, stream>>>(cU, cL, ub + (size_t)i * D, lb + (size_t)i * D,
                                   b_upper + (size_t)i * D, b_lower + (size_t)i * D,
                                   bu, bl, out, w16U, w16L,
                                   W_upper + (size_t)i * DD, W_lower + (size_t)i * DD,
                                   BsT, BdT, 1, 1);
    gemm_fused<<<256, 512, 131072, stream>>>(w16U, w16L, BsT, BdT, curU, curL);
    cU = curU; cL = curL;
  }
  prep<<<2048, 256, 0, stream>>>(cU, cL, ub, lb, b_upper, b_lower,
                                 bu, bl, out, w16U, w16L,
                                 (const float*)nullptr, (const float*)nullptr,
                                 (unsigned short*)nullptr, (unsigned short*)nullptr,
                                 0, 0);
}

// Round 10
// 494.570 us; speedup vs baseline: 1.0325x; 1.0325x over previous
//
#include <hip/hip_runtime.h>

#define D 2048
#define DD ((size_t)D * (size_t)D)

typedef __attribute__((ext_vector_type(8))) short bf16x8;
typedef __attribute__((ext_vector_type(16))) float f32x16;

#define GLOBAL_AS __attribute__((address_space(1)))
#define LDS_AS __attribute__((address_space(3)))

__device__ inline unsigned short f2bf(float f) {
  unsigned u = __float_as_uint(f);
  u += 0x7fffu + ((u >> 16) & 1u);
  return (unsigned short)(u >> 16);
}

// ---------------------------------------------------------------------------
__global__ void init_vecs(const float* __restrict__ b_upper5,
                          const float* __restrict__ b_lower5,
                          const float* __restrict__ ub5,
                          const float* __restrict__ lb5,
                          float* __restrict__ bu, float* __restrict__ bl,
                          float* __restrict__ out) {
  int t = blockIdx.x * blockDim.x + threadIdx.x;
  if (t < D) {
    bu[t] = b_upper5[t];
    bl[t] = b_lower5[t];
    out[t] = ub5[t];
    out[D + t] = lb5[t];
  }
}

// ---------------------------------------------------------------------------
// prep: fused per-iteration prep pass (unchanged, proven).
//   blocks [0, 2048):   concretize row r + write bf16 copies of Wu/Wl rows
//   blocks [2048, 3072): conv_B 64x64 tile -> BsT/BdT (transposed bf16)
// ---------------------------------------------------------------------------
__global__ __launch_bounds__(256) void prep(
    const float* __restrict__ Wu, const float* __restrict__ Wl,
    const float* __restrict__ ubi, const float* __restrict__ lbi,
    const float* __restrict__ bupi, const float* __restrict__ bloi,
    float* __restrict__ bu, float* __restrict__ bl,
    float* __restrict__ best,
    unsigned short* __restrict__ oU, unsigned short* __restrict__ oL,
    const float* __restrict__ Wup, const float* __restrict__ Wlo,
    unsigned short* __restrict__ BsT, unsigned short* __restrict__ BdT,
    int update_bias, int write16) {
  __shared__ float red[4][4];
  __shared__ unsigned short sS[64][68];
  __shared__ unsigned short sD[64][68];

  const int t = threadIdx.x;

  if (blockIdx.x < 2048) {
    const int r = blockIdx.x;
    const size_t base = (size_t)r * D + t * 8;
    const int c = t * 8;

    float4 wu0 = *(const float4*)(Wu + base), wu1 = *(const float4*)(Wu + base + 4);
    float4 wl0 = *(const float4*)(Wl + base), wl1 = *(const float4*)(Wl + base + 4);
    float4 u0 = *(const float4*)(ubi + c),  u1 = *(const float4*)(ubi + c + 4);
    float4 l0 = *(const float4*)(lbi + c),  l1 = *(const float4*)(lbi + c + 4);
    float4 p0 = *(const float4*)(bupi + c), p1 = *(const float4*)(bupi + c + 4);
    float4 n0 = *(const float4*)(bloi + c), n1 = *(const float4*)(bloi + c + 4);

    float wu[8] = {wu0.x, wu0.y, wu0.z, wu0.w, wu1.x, wu1.y, wu1.z, wu1.w};
    float wl[8] = {wl0.x, wl0.y, wl0.z, wl0.w, wl1.x, wl1.y, wl1.z, wl1.w};
    float uu[8] = {u0.x, u0.y, u0.z, u0.w, u1.x, u1.y, u1.z, u1.w};
    float ll[8] = {l0.x, l0.y, l0.z, l0.w, l1.x, l1.y, l1.z, l1.w};
    float pp[8] = {p0.x, p0.y, p0.z, p0.w, p1.x, p1.y, p1.z, p1.w};
    float nn[8] = {n0.x, n0.y, n0.z, n0.w, n1.x, n1.y, n1.z, n1.w};

    float su_c = 0.f, su_b = 0.f, sl_c = 0.f, sl_b = 0.f;
    #pragma unroll
    for (int j = 0; j < 8; ++j) {
      su_c += wu[j] * (wu[j] >= 0.f ? uu[j] : ll[j]);
      su_b += wu[j] * (wu[j] >= 0.f ? pp[j] : nn[j]);
      sl_c += wl[j] * (wl[j] >= 0.f ? ll[j] : uu[j]);
      sl_b += wl[j] * (wl[j] >= 0.f ? nn[j] : pp[j]);
    }

    if (write16) {
      uint4 w;
      w.x = f2bf(wu[0]) | ((unsigned)f2bf(wu[1]) << 16);
      w.y = f2bf(wu[2]) | ((unsigned)f2bf(wu[3]) << 16);
      w.z = f2bf(wu[4]) | ((unsigned)f2bf(wu[5]) << 16);
      w.w = f2bf(wu[6]) | ((unsigned)f2bf(wu[7]) << 16);
      *(uint4*)(oU + base) = w;
      w.x = f2bf(wl[0]) | ((unsigned)f2bf(wl[1]) << 16);
      w.y = f2bf(wl[2]) | ((unsigned)f2bf(wl[3]) << 16);
      w.z = f2bf(wl[4]) | ((unsigned)f2bf(wl[5]) << 16);
      w.w = f2bf(wl[6]) | ((unsigned)f2bf(wl[7]) << 16);
      *(uint4*)(oL + base) = w;
    }

    #pragma unroll
    for (int off = 32; off; off >>= 1) {
      su_c += __shfl_down(su_c, off);
      su_b += __shfl_down(su_b, off);
      sl_c += __shfl_down(sl_c, off);
      sl_b += __shfl_down(sl_b, off);
    }
    int wave = t >> 6;
    if ((t & 63) == 0) {
      red[0][wave] = su_c; red[1][wave] = su_b;
      red[2][wave] = sl_c; red[3][wave] = sl_b;
    }
    __syncthreads();
    if (t == 0) {
      float a = red[0][0] + red[0][1] + red[0][2] + red[0][3];
      float b = red[1][0] + red[1][1] + red[1][2] + red[1][3];
      float cc = red[2][0] + red[2][1] + red[2][2] + red[2][3];
      float d = red[3][0] + red[3][1] + red[3][2] + red[3][3];
      float bu_old = bu[r], bl_old = bl[r];
      best[r]     = fminf(best[r],     a + bu_old);
      best[D + r] = fmaxf(best[D + r], cc + bl_old);
      if (update_bias) {
        bu[r] = b + bu_old;
        bl[r] = d + bl_old;
      }
    }
  } else {
    const int bx = blockIdx.x - 2048;
    const int k0 = (bx >> 5) * 64, c0 = (bx & 31) * 64;
    const int tx = t & 15, ty = t >> 4;
    #pragma unroll
    for (int r = 0; r < 4; ++r) {
      int kk = ty + r * 16;
      size_t g = (size_t)(k0 + kk) * D + c0 + tx * 4;
      float4 up = *(const float4*)(Wup + g);
      float4 lo = *(const float4*)(Wlo + g);
      sS[kk][tx * 4 + 0] = f2bf((up.x + lo.x) * 0.5f);
      sS[kk][tx * 4 + 1] = f2bf((up.y + lo.y) * 0.5f);
      sS[kk][tx * 4 + 2] = f2bf((up.z + lo.z) * 0.5f);
      sS[kk][tx * 4 + 3] = f2bf((up.w + lo.w) * 0.5f);
      sD[kk][tx * 4 + 0] = f2bf((up.x - lo.x) * 0.5f);
      sD[kk][tx * 4 + 1] = f2bf((up.y - lo.y) * 0.5f);
      sD[kk][tx * 4 + 2] = f2bf((up.z - lo.z) * 0.5f);
      sD[kk][tx * 4 + 3] = f2bf((up.w - lo.w) * 0.5f);
    }
    __syncthreads();
    #pragma unroll
    for (int r = 0; r < 4; ++r) {
      int cc = ty + r * 16;
      int kq = tx * 4;
      unsigned a0 = sS[kq + 0][cc] | ((unsigned)sS[kq + 1][cc] << 16);
      unsigned a1 = sS[kq + 2][cc] | ((unsigned)sS[kq + 3][cc] << 16);
      *(uint2*)(BsT + (size_t)(c0 + cc) * D + k0 + kq) = make_uint2(a0, a1);
      a0 = sD[kq + 0][cc] | ((unsigned)sD[kq + 1][cc] << 16);
      a1 = sD[kq + 2][cc] | ((unsigned)sD[kq + 3][cc] << 16);
      *(uint2*)(BdT + (size_t)(c0 + cc) * D + k0 + kq) = make_uint2(a0, a1);
    }
  }
}

// ---------------------------------------------------------------------------
// Fused dual GEMM — counted-vmcnt pipeline (T3+T4+T5), CORRECT swizzle.
// BK=32, 4 LDS buffers x 32KB (streams AU|AL|Bs|Bd, [128 rows][32 k] bf16),
// 3-tiles-deep prefetch. Per tile: s_waitcnt vmcnt(8) (never 0 in steady
// state) + raw s_barrier (no drain), then 2 phases of
// {6 ds_read || 2 glds-issue for t+3 || setprio(1) 8 MFMA setprio(0)}.
// Row = 4 x 16B slots; swizzle f(row)=(row>>1)&3 (NOT row&3: the row-parity
// bank bit must stay independent of the XOR bits) on stage-source and read.
// Read bank-quad = 4*(row&1) + slot^f(row): 8 distinct per 8 rows -> 4-way.
// ---------------------------------------------------------------------------
__global__ __launch_bounds__(512, 2) void gemm_fused(
    const unsigned short* __restrict__ w16U,
    const unsigned short* __restrict__ w16L,
    const unsigned short* __restrict__ BsT,
    const unsigned short* __restrict__ BdT,
    float* __restrict__ Cu, float* __restrict__ Cl) {
  extern __shared__ unsigned char lds[];

  const int bid = blockIdx.x;
  const int vid = (bid & 7) * 32 + (bid >> 3);   // bijective XCD swizzle (256%8==0)
  const int row0 = (vid >> 4) * 128, col0 = (vid & 15) * 128;

  const int tid = threadIdx.x;
  const int lane = tid & 63, wid = tid >> 6;
  const int grp = wid >> 2;            // 0 = upper path, 1 = lower path
  const int w2 = wid & 3;
  const int wr = w2 >> 1, wc = w2 & 1; // 64x64 sub-tile coords
  const int l31 = lane & 31, kh = lane >> 5;

  // staging: per stream, wave wid owns chunk wid (16 rows x 64B = 1KB).
  const int rowc = wid * 16 + (lane >> 2);
  const int swel = ((lane & 3) ^ ((rowc >> 1) & 3)) * 8;  // pre-swizzled source
  const unsigned short* gAU = w16U + (size_t)(row0 + rowc) * D + swel;
  const unsigned short* gAL = w16L + (size_t)(row0 + rowc) * D + swel;
  const unsigned short* gBs = BsT + (size_t)(col0 + rowc) * D + swel;
  const unsigned short* gBd = BdT + (size_t)(col0 + rowc) * D + swel;

  f32x16 acc[2][2] = {};

  // fragment byte offsets within a stream (row*64B, slot=(ks*2+kh)^f(row))
  int aoff[2][2], boff[2][2];
  #pragma unroll
  for (int mb = 0; mb < 2; ++mb) {
    int ar = wr * 64 + mb * 32 + l31;
    #pragma unroll
    for (int ks = 0; ks < 2; ++ks)
      aoff[mb][ks] = ar * 64 + (((ks * 2 + kh) ^ ((ar >> 1) & 3)) * 16);
  }
  #pragma unroll
  for (int nb = 0; nb < 2; ++nb) {
    int bc = wc * 64 + nb * 32 + l31;
    #pragma unroll
    for (int ks = 0; ks < 2; ++ks)
      boff[nb][ks] = bc * 64 + (((ks * 2 + kh) ^ ((bc >> 1) & 3)) * 16);
  }

  #define STAGE_A(buf, kt)                                                        \
    do {                                                                          \
      unsigned dst = (unsigned)(buf) * 32768u + (unsigned)wid * 1024u;            \
      __builtin_amdgcn_global_load_lds((const GLOBAL_AS unsigned*)(gAU + (kt)),   \
          (LDS_AS unsigned*)(lds + 0 + dst), 16, 0, 0);                           \
      __builtin_amdgcn_global_load_lds((const GLOBAL_AS unsigned*)(gAL + (kt)),   \
          (LDS_AS unsigned*)(lds + 8192 + dst), 16, 0, 0);                        \
    } while (0)
  #define STAGE_B(buf, kt)                                                        \
    do {                                                                          \
      unsigned dst = (unsigned)(buf) * 32768u + (unsigned)wid * 1024u;            \
      __builtin_amdgcn_global_load_lds((const GLOBAL_AS unsigned*)(gBs + (kt)),   \
          (LDS_AS unsigned*)(lds + 16384 + dst), 16, 0, 0);                       \
      __builtin_amdgcn_global_load_lds((const GLOBAL_AS unsigned*)(gBd + (kt)),   \
          (LDS_AS unsigned*)(lds + 24576 + dst), 16, 0, 0);                       \
    } while (0)

  // prologue: stage tiles 0,1,2 into buffers 0,1,2 (12 loads in flight)
  STAGE_A(0, 0);  STAGE_B(0, 0);
  STAGE_A(1, 32); STAGE_B(1, 32);
  STAGE_A(2, 64); STAGE_B(2, 64);

  const unsigned Abase = grp ? 8192u : 0u;
  for (int t = 0; t < 64; ++t) {
    // wait for tile t's 4 loads only; keep t+1, t+2 in flight
    if (t < 62)       asm volatile("s_waitcnt vmcnt(8)" ::: "memory");
    else if (t == 62) asm volatile("s_waitcnt vmcnt(4)" ::: "memory");
    else              asm volatile("s_waitcnt vmcnt(0)" ::: "memory");
    __builtin_amdgcn_s_barrier();

    const unsigned char* Ab = lds + Abase + (t & 3) * 32768;
    const unsigned char* Sb = lds + 16384 + (t & 3) * 32768;
    const unsigned char* Db = lds + 24576 + (t & 3) * 32768;
    const bool do_stage = (t <= 60);

    #pragma unroll
    for (int ks = 0; ks < 2; ++ks) {
      bf16x8 aw0 = *(const bf16x8*)(Ab + aoff[0][ks]);
      bf16x8 aw1 = *(const bf16x8*)(Ab + aoff[1][ks]);
      bf16x8 bs0 = *(const bf16x8*)(Sb + boff[0][ks]);
      bf16x8 bs1 = *(const bf16x8*)(Sb + boff[1][ks]);
      bf16x8 bd0 = *(const bf16x8*)(Db + boff[0][ks]);
      bf16x8 bd1 = *(const bf16x8*)(Db + boff[1][ks]);

      if (do_stage) {
        if (ks == 0) STAGE_A((t + 3) & 3, (t + 3) * 32);
        else         STAGE_B((t + 3) & 3, (t + 3) * 32);
      }

      if (grp) { bd0 ^= (short)0x8000; bd1 ^= (short)0x8000; }
      bf16x8 av0 = aw0 & (short)0x7fff;
      bf16x8 av1 = aw1 & (short)0x7fff;

      __builtin_amdgcn_s_setprio(1);
      acc[0][0] = __builtin_amdgcn_mfma_f32_32x32x16_bf16(aw0, bs0, acc[0][0], 0, 0, 0);
      acc[0][0] = __builtin_amdgcn_mfma_f32_32x32x16_bf16(av0, bd0, acc[0][0], 0, 0, 0);
      acc[0][1] = __builtin_amdgcn_mfma_f32_32x32x16_bf16(aw0, bs1, acc[0][1], 0, 0, 0);
      acc[0][1] = __builtin_amdgcn_mfma_f32_32x32x16_bf16(av0, bd1, acc[0][1], 0, 0, 0);
      acc[1][0] = __builtin_amdgcn_mfma_f32_32x32x16_bf16(aw1, bs0, acc[1][0], 0, 0, 0);
      acc[1][0] = __builtin_amdgcn_mfma_f32_32x32x16_bf16(av1, bd0, acc[1][0], 0, 0, 0);
      acc[1][1] = __builtin_amdgcn_mfma_f32_32x32x16_bf16(aw1, bs1, acc[1][1], 0, 0, 0);
      acc[1][1] = __builtin_amdgcn_mfma_f32_32x32x16_bf16(av1, bd1, acc[1][1], 0, 0, 0);
      __builtin_amdgcn_s_setprio(0);
    }
  }
  #undef STAGE_A
  #undef STAGE_B

  // epilogue: C/D layout col=lane&31, row=(reg&3)+8*(reg>>2)+4*(lane>>5)
  float* C = grp ? Cl : Cu;
  #pragma unroll
  for (int mb = 0; mb < 2; ++mb)
    #pragma unroll
    for (int nb = 0; nb < 2; ++nb) {
      const int colg = col0 + wc * 64 + nb * 32 + l31;
      const int rowb = row0 + wr * 64 + mb * 32 + kh * 4;
      #pragma unroll
      for (int g = 0; g < 4; ++g)
        #pragma unroll
        for (int j = 0; j < 4; ++j)
          C[(size_t)(rowb + g * 8 + j) * D + colg] = acc[mb][nb][g * 4 + j];
    }
}

// ---------------------------------------------------------------------------
extern "C" void kernel_launch(void* const* d_in, const int* in_sizes, int n_in,
                              void* d_out, int out_size, void* d_ws, size_t ws_size,
                              hipStream_t stream) {
  const float* W_upper = (const float*)d_in[0];
  const float* W_lower = (const float*)d_in[1];
  const float* b_upper = (const float*)d_in[2];
  const float* b_lower = (const float*)d_in[3];
  const float* ub      = (const float*)d_in[4];
  const float* lb      = (const float*)d_in[5];
  float* out = (float*)d_out;
  float* ws  = (float*)d_ws;

  float* curU = ws;                                       // DD f32
  float* curL = ws + DD;                                  // DD f32
  unsigned short* w16U = (unsigned short*)(ws + 2 * DD);  // DD bf16
  unsigned short* w16L = w16U + DD;
  unsigned short* BsT  = w16L + DD;
  unsigned short* BdT  = BsT + DD;
  float* bu = (float*)(BdT + DD);                         // D f32
  float* bl = bu + D;

  static_cast<void>(hipFuncSetAttribute(
      (const void*)gemm_fused, hipFuncAttributeMaxDynamicSharedMemorySize, 131072));

  init_vecs<<<(D + 255) / 256, 256, 0, stream>>>(
      b_upper + 5 * D, b_lower + 5 * D, ub + 5 * D, lb + 5 * D, bu, bl, out);

  const float* cU = W_upper + 5 * DD;
  const float* cL = W_lower + 5 * DD;
  for (int i = 4; i >= 0; --i) {
    prep<<<3072, 256, 0, stream>>>(cU, cL, ub + (size_t)i * D, lb + (size_t)i * D,
                                   b_upper + (size_t)i * D, b_lower + (size_t)i * D,
                                   bu, bl, out, w16U, w16L,
                                   W_upper + (size_t)i * DD, W_lower + (size_t)i * DD,
                                   BsT, BdT, 1, 1);
    gemm_fused<<<256, 512, 131072, stream>>>(w16U, w16L, BsT, BdT, curU, curL);
    cU = curU; cL = curL;
  }
  prep<<<2048, 256, 0, stream>>>(cU, cL, ub, lb, b_upper, b_lower,
                                 bu, bl, out, w16U, w16L,
                                 (const float*)nullptr, (const float*)nullptr,
                                 (unsigned short*)nullptr, (unsigned short*)nullptr,
                                 0, 0);
}

// Round 11
// 490.524 us; speedup vs baseline: 1.0410x; 1.0082x over previous
//
#include <hip/hip_runtime.h>

#define D 2048
#define DD ((size_t)D * (size_t)D)

typedef __attribute__((ext_vector_type(8))) short bf16x8;
typedef __attribute__((ext_vector_type(16))) float f32x16;

#define GLOBAL_AS __attribute__((address_space(1)))
#define LDS_AS __attribute__((address_space(3)))

__device__ inline unsigned short f2bf(float f) {
  unsigned u = __float_as_uint(f);
  u += 0x7fffu + ((u >> 16) & 1u);
  return (unsigned short)(u >> 16);
}

// ---------------------------------------------------------------------------
__global__ void init_vecs(const float* __restrict__ b_upper5,
                          const float* __restrict__ b_lower5,
                          const float* __restrict__ ub5,
                          const float* __restrict__ lb5,
                          float* __restrict__ bu, float* __restrict__ bl,
                          float* __restrict__ out) {
  int t = blockIdx.x * blockDim.x + threadIdx.x;
  if (t < D) {
    bu[t] = b_upper5[t];
    bl[t] = b_lower5[t];
    out[t] = ub5[t];
    out[D + t] = lb5[t];
  }
}

// ---------------------------------------------------------------------------
// prep: fused per-iteration prep pass (unchanged, proven).
//   blocks [0, 2048):   concretize row r + write bf16 copies of Wu/Wl rows
//   blocks [2048, 3072): conv_B 64x64 tile -> BsT/BdT (transposed bf16)
// ---------------------------------------------------------------------------
__global__ __launch_bounds__(256) void prep(
    const float* __restrict__ Wu, const float* __restrict__ Wl,
    const float* __restrict__ ubi, const float* __restrict__ lbi,
    const float* __restrict__ bupi, const float* __restrict__ bloi,
    float* __restrict__ bu, float* __restrict__ bl,
    float* __restrict__ best,
    unsigned short* __restrict__ oU, unsigned short* __restrict__ oL,
    const float* __restrict__ Wup, const float* __restrict__ Wlo,
    unsigned short* __restrict__ BsT, unsigned short* __restrict__ BdT,
    int update_bias, int write16) {
  __shared__ float red[4][4];
  __shared__ unsigned short sS[64][68];
  __shared__ unsigned short sD[64][68];

  const int t = threadIdx.x;

  if (blockIdx.x < 2048) {
    const int r = blockIdx.x;
    const size_t base = (size_t)r * D + t * 8;
    const int c = t * 8;

    float4 wu0 = *(const float4*)(Wu + base), wu1 = *(const float4*)(Wu + base + 4);
    float4 wl0 = *(const float4*)(Wl + base), wl1 = *(const float4*)(Wl + base + 4);
    float4 u0 = *(const float4*)(ubi + c),  u1 = *(const float4*)(ubi + c + 4);
    float4 l0 = *(const float4*)(lbi + c),  l1 = *(const float4*)(lbi + c + 4);
    float4 p0 = *(const float4*)(bupi + c), p1 = *(const float4*)(bupi + c + 4);
    float4 n0 = *(const float4*)(bloi + c), n1 = *(const float4*)(bloi + c + 4);

    float wu[8] = {wu0.x, wu0.y, wu0.z, wu0.w, wu1.x, wu1.y, wu1.z, wu1.w};
    float wl[8] = {wl0.x, wl0.y, wl0.z, wl0.w, wl1.x, wl1.y, wl1.z, wl1.w};
    float uu[8] = {u0.x, u0.y, u0.z, u0.w, u1.x, u1.y, u1.z, u1.w};
    float ll[8] = {l0.x, l0.y, l0.z, l0.w, l1.x, l1.y, l1.z, l1.w};
    float pp[8] = {p0.x, p0.y, p0.z, p0.w, p1.x, p1.y, p1.z, p1.w};
    float nn[8] = {n0.x, n0.y, n0.z, n0.w, n1.x, n1.y, n1.z, n1.w};

    float su_c = 0.f, su_b = 0.f, sl_c = 0.f, sl_b = 0.f;
    #pragma unroll
    for (int j = 0; j < 8; ++j) {
      su_c += wu[j] * (wu[j] >= 0.f ? uu[j] : ll[j]);
      su_b += wu[j] * (wu[j] >= 0.f ? pp[j] : nn[j]);
      sl_c += wl[j] * (wl[j] >= 0.f ? ll[j] : uu[j]);
      sl_b += wl[j] * (wl[j] >= 0.f ? nn[j] : pp[j]);
    }

    if (write16) {
      uint4 w;
      w.x = f2bf(wu[0]) | ((unsigned)f2bf(wu[1]) << 16);
      w.y = f2bf(wu[2]) | ((unsigned)f2bf(wu[3]) << 16);
      w.z = f2bf(wu[4]) | ((unsigned)f2bf(wu[5]) << 16);
      w.w = f2bf(wu[6]) | ((unsigned)f2bf(wu[7]) << 16);
      *(uint4*)(oU + base) = w;
      w.x = f2bf(wl[0]) | ((unsigned)f2bf(wl[1]) << 16);
      w.y = f2bf(wl[2]) | ((unsigned)f2bf(wl[3]) << 16);
      w.z = f2bf(wl[4]) | ((unsigned)f2bf(wl[5]) << 16);
      w.w = f2bf(wl[6]) | ((unsigned)f2bf(wl[7]) << 16);
      *(uint4*)(oL + base) = w;
    }

    #pragma unroll
    for (int off = 32; off; off >>= 1) {
      su_c += __shfl_down(su_c, off);
      su_b += __shfl_down(su_b, off);
      sl_c += __shfl_down(sl_c, off);
      sl_b += __shfl_down(sl_b, off);
    }
    int wave = t >> 6;
    if ((t & 63) == 0) {
      red[0][wave] = su_c; red[1][wave] = su_b;
      red[2][wave] = sl_c; red[3][wave] = sl_b;
    }
    __syncthreads();
    if (t == 0) {
      float a = red[0][0] + red[0][1] + red[0][2] + red[0][3];
      float b = red[1][0] + red[1][1] + red[1][2] + red[1][3];
      float cc = red[2][0] + red[2][1] + red[2][2] + red[2][3];
      float d = red[3][0] + red[3][1] + red[3][2] + red[3][3];
      float bu_old = bu[r], bl_old = bl[r];
      best[r]     = fminf(best[r],     a + bu_old);
      best[D + r] = fmaxf(best[D + r], cc + bl_old);
      if (update_bias) {
        bu[r] = b + bu_old;
        bl[r] = d + bl_old;
      }
    }
  } else {
    const int bx = blockIdx.x - 2048;
    const int k0 = (bx >> 5) * 64, c0 = (bx & 31) * 64;
    const int tx = t & 15, ty = t >> 4;
    #pragma unroll
    for (int r = 0; r < 4; ++r) {
      int kk = ty + r * 16;
      size_t g = (size_t)(k0 + kk) * D + c0 + tx * 4;
      float4 up = *(const float4*)(Wup + g);
      float4 lo = *(const float4*)(Wlo + g);
      sS[kk][tx * 4 + 0] = f2bf((up.x + lo.x) * 0.5f);
      sS[kk][tx * 4 + 1] = f2bf((up.y + lo.y) * 0.5f);
      sS[kk][tx * 4 + 2] = f2bf((up.z + lo.z) * 0.5f);
      sS[kk][tx * 4 + 3] = f2bf((up.w + lo.w) * 0.5f);
      sD[kk][tx * 4 + 0] = f2bf((up.x - lo.x) * 0.5f);
      sD[kk][tx * 4 + 1] = f2bf((up.y - lo.y) * 0.5f);
      sD[kk][tx * 4 + 2] = f2bf((up.z - lo.z) * 0.5f);
      sD[kk][tx * 4 + 3] = f2bf((up.w - lo.w) * 0.5f);
    }
    __syncthreads();
    #pragma unroll
    for (int r = 0; r < 4; ++r) {
      int cc = ty + r * 16;
      int kq = tx * 4;
      unsigned a0 = sS[kq + 0][cc] | ((unsigned)sS[kq + 1][cc] << 16);
      unsigned a1 = sS[kq + 2][cc] | ((unsigned)sS[kq + 3][cc] << 16);
      *(uint2*)(BsT + (size_t)(c0 + cc) * D + k0 + kq) = make_uint2(a0, a1);
      a0 = sD[kq + 0][cc] | ((unsigned)sD[kq + 1][cc] << 16);
      a1 = sD[kq + 2][cc] | ((unsigned)sD[kq + 3][cc] << 16);
      *(uint2*)(BdT + (size_t)(c0 + cc) * D + k0 + kq) = make_uint2(a0, a1);
    }
  }
}

// ---------------------------------------------------------------------------
// Fused dual GEMM — m201-style fine-grained phase interleave on the R8 frame.
// BK=64, 2 LDS buffers x 64KB (streams AU|AL|Bs|Bd, [128 rows][64 k] bf16),
// half-tile staging (4 glds/wave per half), 1.5-tile prefetch.
// Per K-tile: STAGE(t+1,h0); vmcnt(4) counted (0 only at t=31); barrier;
// then 4 phases of {6 ds_read; (p==2: STAGE(t+1,h1)); barrier; lgkmcnt(0)
// + sched_barrier; setprio(1) 8 MFMA setprio(0); barrier}.
// Swizzle slot^(row&7) on stage-source and read (R8-verified, 4-way floor).
// ---------------------------------------------------------------------------
__global__ __launch_bounds__(512, 2) void gemm_fused(
    const unsigned short* __restrict__ w16U,
    const unsigned short* __restrict__ w16L,
    const unsigned short* __restrict__ BsT,
    const unsigned short* __restrict__ BdT,
    float* __restrict__ Cu, float* __restrict__ Cl) {
  extern __shared__ unsigned char lds[];

  const int bid = blockIdx.x;
  const int vid = (bid & 7) * 32 + (bid >> 3);   // bijective XCD swizzle (256%8==0)
  const int row0 = (vid >> 4) * 128, col0 = (vid & 15) * 128;

  const int tid = threadIdx.x;
  const int lane = tid & 63, wid = tid >> 6;
  const int grp = wid >> 2;            // 0 = upper path, 1 = lower path
  const int w2 = wid & 3;
  const int wr = w2 >> 1, wc = w2 & 1; // 64x64 sub-tile coords
  const int l31 = lane & 31, kh = lane >> 5;

  // staging (per half-tile of 64 rows): wave wid owns rows [wid*8 .. wid*8+7]
  // of the half; lane l -> row wid*8 + (l>>3), slot l&7 (8 x 16B = 128B row).
  const int rowh = wid * 8 + (lane >> 3);        // row within half (0..63)
  const int slot = lane & 7;
  const int swel = (slot ^ (rowh & 7)) * 8;      // pre-swizzled source elems
  const unsigned short* gAU = w16U + (size_t)(row0 + rowh) * D + swel;
  const unsigned short* gAL = w16L + (size_t)(row0 + rowh) * D + swel;
  const unsigned short* gBs = BsT + (size_t)(col0 + rowh) * D + swel;
  const unsigned short* gBd = BdT + (size_t)(col0 + rowh) * D + swel;

  f32x16 acc[2][2] = {};

  // fragment byte offsets within a stream buffer (row*128B, 8 slots/row)
  int aoff[2][4], boff[2][4];
  #pragma unroll
  for (int mb = 0; mb < 2; ++mb) {
    int ar = wr * 64 + mb * 32 + l31;
    #pragma unroll
    for (int ks = 0; ks < 4; ++ks)
      aoff[mb][ks] = ar * 128 + (((ks * 2 + kh) ^ (ar & 7)) * 16);
  }
  #pragma unroll
  for (int nb = 0; nb < 2; ++nb) {
    int bc = wc * 64 + nb * 32 + l31;
    #pragma unroll
    for (int ks = 0; ks < 4; ++ks)
      boff[nb][ks] = bc * 128 + (((ks * 2 + kh) ^ (bc & 7)) * 16);
  }

  // half h of tile with K-offset kt into LDS buffer bu_: dst = stream base
  // + bu_*65536 + h*8192 + wid*1024; src = gX + h*64*D + kt.
  #define STAGE_HALF(bu_, h, kt)                                                   \
    do {                                                                           \
      unsigned dst = (unsigned)(bu_) * 65536u + (unsigned)(h) * 8192u +            \
                     (unsigned)wid * 1024u;                                        \
      size_t so = (size_t)(h) * 64 * D + (size_t)(kt);                             \
      __builtin_amdgcn_global_load_lds((const GLOBAL_AS unsigned*)(gAU + so),      \
          (LDS_AS unsigned*)(lds + 0 + dst), 16, 0, 0);                            \
      __builtin_amdgcn_global_load_lds((const GLOBAL_AS unsigned*)(gAL + so),      \
          (LDS_AS unsigned*)(lds + 16384 + dst), 16, 0, 0);                        \
      __builtin_amdgcn_global_load_lds((const GLOBAL_AS unsigned*)(gBs + so),      \
          (LDS_AS unsigned*)(lds + 32768 + dst), 16, 0, 0);                        \
      __builtin_amdgcn_global_load_lds((const GLOBAL_AS unsigned*)(gBd + so),      \
          (LDS_AS unsigned*)(lds + 49152 + dst), 16, 0, 0);                        \
    } while (0)

  // prologue: stage tile 0 (both halves) into buffer 0 -> 8 loads in flight
  STAGE_HALF(0, 0, 0);
  STAGE_HALF(0, 1, 0);

  const unsigned Abase = grp ? 16384u : 0u;
  for (int t = 0; t < 32; ++t) {
    const int buf = t & 1;
    // issue next tile's first half, then counted drain of tile t's 8 loads
    if (t < 31) {
      STAGE_HALF(buf ^ 1, 0, (t + 1) * 64);
      asm volatile("s_waitcnt vmcnt(4)" ::: "memory");
    } else {
      asm volatile("s_waitcnt vmcnt(0)" ::: "memory");
    }
    __builtin_amdgcn_s_barrier();

    const unsigned char* Ab = lds + Abase + (unsigned)buf * 65536u;
    const unsigned char* Sb = lds + 32768u + (unsigned)buf * 65536u;
    const unsigned char* Db = lds + 49152u + (unsigned)buf * 65536u;

    #pragma unroll
    for (int p = 0; p < 4; ++p) {
      bf16x8 aw0 = *(const bf16x8*)(Ab + aoff[0][p]);
      bf16x8 aw1 = *(const bf16x8*)(Ab + aoff[1][p]);
      bf16x8 bs0 = *(const bf16x8*)(Sb + boff[0][p]);
      bf16x8 bs1 = *(const bf16x8*)(Sb + boff[1][p]);
      bf16x8 bd0 = *(const bf16x8*)(Db + boff[0][p]);
      bf16x8 bd1 = *(const bf16x8*)(Db + boff[1][p]);

      if (p == 2 && t < 31) STAGE_HALF(buf ^ 1, 1, (t + 1) * 64);

      __builtin_amdgcn_s_barrier();
      asm volatile("s_waitcnt lgkmcnt(0)" ::: "memory");
      __builtin_amdgcn_sched_barrier(0);

      if (grp) { bd0 ^= (short)0x8000; bd1 ^= (short)0x8000; }
      bf16x8 av0 = aw0 & (short)0x7fff;
      bf16x8 av1 = aw1 & (short)0x7fff;

      __builtin_amdgcn_s_setprio(1);
      acc[0][0] = __builtin_amdgcn_mfma_f32_32x32x16_bf16(aw0, bs0, acc[0][0], 0, 0, 0);
      acc[0][0] = __builtin_amdgcn_mfma_f32_32x32x16_bf16(av0, bd0, acc[0][0], 0, 0, 0);
      acc[0][1] = __builtin_amdgcn_mfma_f32_32x32x16_bf16(aw0, bs1, acc[0][1], 0, 0, 0);
      acc[0][1] = __builtin_amdgcn_mfma_f32_32x32x16_bf16(av0, bd1, acc[0][1], 0, 0, 0);
      acc[1][0] = __builtin_amdgcn_mfma_f32_32x32x16_bf16(aw1, bs0, acc[1][0], 0, 0, 0);
      acc[1][0] = __builtin_amdgcn_mfma_f32_32x32x16_bf16(av1, bd0, acc[1][0], 0, 0, 0);
      acc[1][1] = __builtin_amdgcn_mfma_f32_32x32x16_bf16(aw1, bs1, acc[1][1], 0, 0, 0);
      acc[1][1] = __builtin_amdgcn_mfma_f32_32x32x16_bf16(av1, bd1, acc[1][1], 0, 0, 0);
      __builtin_amdgcn_s_setprio(0);
      __builtin_amdgcn_s_barrier();
    }
  }
  #undef STAGE_HALF

  // epilogue: C/D layout col=lane&31, row=(reg&3)+8*(reg>>2)+4*(lane>>5)
  float* C = grp ? Cl : Cu;
  #pragma unroll
  for (int mb = 0; mb < 2; ++mb)
    #pragma unroll
    for (int nb = 0; nb < 2; ++nb) {
      const int colg = col0 + wc * 64 + nb * 32 + l31;
      const int rowb = row0 + wr * 64 + mb * 32 + kh * 4;
      #pragma unroll
      for (int g = 0; g < 4; ++g)
        #pragma unroll
        for (int j = 0; j < 4; ++j)
          C[(size_t)(rowb + g * 8 + j) * D + colg] = acc[mb][nb][g * 4 + j];
    }
}

// ---------------------------------------------------------------------------
extern "C" void kernel_launch(void* const* d_in, const int* in_sizes, int n_in,
                              void* d_out, int out_size, void* d_ws, size_t ws_size,
                              hipStream_t stream) {
  const float* W_upper = (const float*)d_in[0];
  const float* W_lower = (const float*)d_in[1];
  const float* b_upper = (const float*)d_in[2];
  const float* b_lower = (const float*)d_in[3];
  const float* ub      = (const float*)d_in[4];
  const float* lb      = (const float*)d_in[5];
  float* out = (float*)d_out;
  float* ws  = (float*)d_ws;

  float* curU = ws;                                       // DD f32
  float* curL = ws + DD;                                  // DD f32
  unsigned short* w16U = (unsigned short*)(ws + 2 * DD);  // DD bf16
  unsigned short* w16L = w16U + DD;
  unsigned short* BsT  = w16L + DD;
  unsigned short* BdT  = BsT + DD;
  float* bu = (float*)(BdT + DD);                         // D f32
  float* bl = bu + D;

  static_cast<void>(hipFuncSetAttribute(
      (const void*)gemm_fused, hipFuncAttributeMaxDynamicSharedMemorySize, 131072));

  init_vecs<<<(D + 255) / 256, 256, 0, stream>>>(
      b_upper + 5 * D, b_lower + 5 * D, ub + 5 * D, lb + 5 * D, bu, bl, out);

  const float* cU = W_upper + 5 * DD;
  const float* cL = W_lower + 5 * DD;
  for (int i = 4; i >= 0; --i) {
    prep<<<3072, 256, 0, stream>>>(cU, cL, ub + (size_t)i * D, lb + (size_t)i * D,
                                   b_upper + (size_t)i * D, b_lower + (size_t)i * D,
                                   bu, bl, out, w16U, w16L,
                                   W_upper + (size_t)i * DD, W_lower + (size_t)i * DD,
                                   BsT, BdT, 1, 1);
    gemm_fused<<<256, 512, 131072, stream>>>(w16U, w16L, BsT, BdT, curU, curL);
    cU = curU; cL = curL;
  }
  prep<<<2048, 256, 0, stream>>>(cU, cL, ub, lb, b_upper, b_lower,
                                 bu, bl, out, w16U, w16L,
                                 (const float*)nullptr, (const float*)nullptr,
                                 (unsigned short*)nullptr, (unsigned short*)nullptr,
                                 0, 0);
}